// Round 2
// baseline (1366.682 us; speedup 1.0000x reference)
//
#include <hip/hip_runtime.h>

// All tensors are float32 (verified via npz sizes: 31 MB in / 3.5 MB out).
//
// Math structure exploited:
//  - softmax over axis of size 1 == 1.0  -> attn is all-ones, Wa/ba dead.
//  - weighted[j] = sum_d tanh(agg)[j,d]  (row-sum), broadcast over COLUMNS
//    (N==D quirk): lig[i,j] = nf[i,j] + w[j].
//  - lig_p = lig@Wl.T = nf@Wl.T + cL  (cL[h] = sum_j w[j] Wl[h,j], rank-0 in i)
//  - x0[h,i,j] = PL[i,h] + PR[j,h] + c[h]  -> generated on the fly inside a
//    fully fused conv1+relu -> conv2+relu -> conv3 kernel. No 128MB tensor.

// ---------------------------------------------------------------------------
// K1: agg = tanh(nf@Wn.T + bn + ef@We.T + be); partial row-sums over d-blocks.
// Tiled f32 GEMM: BM=128 (rows j), BN=64 (cols d), BK=32, 256 thr, micro 8x4.
// part[cx][dblk][row] written deterministically (no atomics). grid (8,16,2)
// ---------------------------------------------------------------------------
__global__ __launch_bounds__(256) void gnn_kernel(
    const float* __restrict__ lig_nf, const float* __restrict__ lig_ef,
    const float* __restrict__ rec_nf, const float* __restrict__ rec_ef,
    const float* __restrict__ Wn, const float* __restrict__ We,
    const float* __restrict__ bn, const float* __restrict__ be,
    float* __restrict__ part)   // [2][16][1024]
{
    __shared__ float As[32][128];
    __shared__ float Bs[32][64];
    const int t  = threadIdx.x;
    const int cx = blockIdx.z;
    const float* A0 = cx ? rec_nf : lig_nf;
    const float* A1 = cx ? rec_ef : lig_ef;
    const int j0 = blockIdx.x * 128;
    const int d0 = blockIdx.y * 64;

    float acc[8][4];
    #pragma unroll
    for (int i = 0; i < 8; ++i)
        #pragma unroll
        for (int j = 0; j < 4; ++j) acc[i][j] = 0.f;

    const int ty = t >> 4;   // 0..15 -> rows ty*8..+8
    const int tx = t & 15;   // cols tx*4..+4

    for (int kt = 0; kt < 64; ++kt){
        const float* Asrc = (kt < 32) ? A0 : A1;
        const float* Bsrc = (kt < 32) ? Wn : We;
        const int kb = (kt & 31) * 32;
        // stage A: 128 rows x 32 k   (1024 float4, 4 per thread)
        #pragma unroll
        for (int p = 0; p < 4; ++p){
            int u   = t + 256 * p;
            int row = u >> 3;
            int kc  = (u & 7) * 4;
            float4 v = *reinterpret_cast<const float4*>(Asrc + (size_t)(j0 + row) * 1024 + kb + kc);
            As[kc + 0][row] = v.x; As[kc + 1][row] = v.y;
            As[kc + 2][row] = v.z; As[kc + 3][row] = v.w;
        }
        // stage B: 64 rows x 32 k    (512 float4, 2 per thread)
        #pragma unroll
        for (int p = 0; p < 2; ++p){
            int u   = t + 256 * p;
            int row = u >> 3;
            int kc  = (u & 7) * 4;
            float4 v = *reinterpret_cast<const float4*>(Bsrc + (size_t)(d0 + row) * 1024 + kb + kc);
            Bs[kc + 0][row] = v.x; Bs[kc + 1][row] = v.y;
            Bs[kc + 2][row] = v.z; Bs[kc + 3][row] = v.w;
        }
        __syncthreads();
        #pragma unroll
        for (int kk = 0; kk < 32; ++kk){
            float4 a0 = *reinterpret_cast<const float4*>(&As[kk][ty * 8]);
            float4 a1 = *reinterpret_cast<const float4*>(&As[kk][ty * 8 + 4]);
            float4 b  = *reinterpret_cast<const float4*>(&Bs[kk][tx * 4]);
            float av[8] = {a0.x, a0.y, a0.z, a0.w, a1.x, a1.y, a1.z, a1.w};
            float bv[4] = {b.x, b.y, b.z, b.w};
            #pragma unroll
            for (int i = 0; i < 8; ++i)
                #pragma unroll
                for (int j = 0; j < 4; ++j)
                    acc[i][j] = fmaf(av[i], bv[j], acc[i][j]);
        }
        __syncthreads();
    }

    // epilogue: bias + tanh + reduce over this block's 64 d-columns
    float rsum[8];
    #pragma unroll
    for (int i = 0; i < 8; ++i) rsum[i] = 0.f;
    #pragma unroll
    for (int j = 0; j < 4; ++j){
        int d = d0 + tx * 4 + j;
        float bias = bn[d] + be[d];
        #pragma unroll
        for (int i = 0; i < 8; ++i)
            rsum[i] += tanhf(acc[i][j] + bias);
    }
    #pragma unroll
    for (int m = 1; m < 16; m <<= 1)
        #pragma unroll
        for (int i = 0; i < 8; ++i)
            rsum[i] += __shfl_xor(rsum[i], m);
    if (tx == 0){
        float* p = part + (size_t)cx * 16384 + (size_t)blockIdx.y * 1024;
        #pragma unroll
        for (int i = 0; i < 8; ++i)
            p[j0 + ty * 8 + i] = rsum[i];
    }
}

// ---------------------------------------------------------------------------
// K2a: PL[i,h] = sum_j nf[i,j]*Wl[h,j]; PR analog (rec, Wr).
// grid (128, 2), block 256: h = t&31, i = bx*8 + t>>5
// ---------------------------------------------------------------------------
__global__ __launch_bounds__(256) void proj_kernel(
    const float* __restrict__ lig_nf, const float* __restrict__ rec_nf,
    const float* __restrict__ W_hopi, float* __restrict__ PL, float* __restrict__ PR)
{
    const int t  = threadIdx.x;
    const int cx = blockIdx.y;
    const float* nf = cx ? rec_nf : lig_nf;
    const float* W  = W_hopi + (cx ? 1024 : 0);
    float* outp     = cx ? PR : PL;
    const int h = t & 31;
    const int i = blockIdx.x * 8 + (t >> 5);
    const float* nrow = nf + (size_t)i * 1024;
    const float* wrow = W + (size_t)h * 2048;
    float s0 = 0.f, s1 = 0.f;
    #pragma unroll 4
    for (int j = 0; j < 1024; j += 8){
        float4 a0 = *reinterpret_cast<const float4*>(nrow + j);
        float4 b0 = *reinterpret_cast<const float4*>(wrow + j);
        float4 a1 = *reinterpret_cast<const float4*>(nrow + j + 4);
        float4 b1 = *reinterpret_cast<const float4*>(wrow + j + 4);
        s0 = fmaf(a0.x, b0.x, s0); s0 = fmaf(a0.y, b0.y, s0);
        s0 = fmaf(a0.z, b0.z, s0); s0 = fmaf(a0.w, b0.w, s0);
        s1 = fmaf(a1.x, b1.x, s1); s1 = fmaf(a1.y, b1.y, s1);
        s1 = fmaf(a1.z, b1.z, s1); s1 = fmaf(a1.w, b1.w, s1);
    }
    outp[(size_t)i * 32 + h] = s0 + s1;
}

// ---------------------------------------------------------------------------
// K2b: w[j] = sum over 16 part blocks; c[h] = b_hopi[h] + wL.Wl[h] + wR.Wr[h]
// single block 256
// ---------------------------------------------------------------------------
__global__ __launch_bounds__(256) void cvec_kernel(
    const float* __restrict__ W_hopi, const float* __restrict__ b_hopi,
    const float* __restrict__ part, float* __restrict__ cvec)
{
    __shared__ float ws_l[1024];
    __shared__ float ws_r[1024];
    __shared__ float red[256];
    const int t = threadIdx.x;
    for (int j = t; j < 1024; j += 256){
        float sl = 0.f, sr = 0.f;
        #pragma unroll
        for (int b = 0; b < 16; ++b){
            sl += part[b * 1024 + j];
            sr += part[16384 + b * 1024 + j];
        }
        ws_l[j] = sl; ws_r[j] = sr;
    }
    __syncthreads();
    const int h = t & 31;
    const int seg = t >> 5;      // 8 segments of 128 j's
    float s = 0.f;
    for (int j = seg * 128; j < seg * 128 + 128; ++j){
        s = fmaf(ws_l[j], W_hopi[(size_t)h * 2048 + j], s);
        s = fmaf(ws_r[j], W_hopi[(size_t)h * 2048 + 1024 + j], s);
    }
    red[t] = s;
    __syncthreads();
    if (t < 32){
        float tot = b_hopi[t];
        #pragma unroll
        for (int g = 0; g < 8; ++g) tot += red[g * 32 + t];
        cvec[t] = tot;
    }
}

// ---------------------------------------------------------------------------
// K3: fused conv1(3x3,32->32)+relu -> conv2(3x3,32->32)+relu -> conv3(1x1)
// x0 generated on the fly: x0[ci,a,b] = PL[a,ci] + PR[b,ci] + c[ci] (0 outside)
// block = 256 (4 waves = 4 co-groups of 8), 16x16 output tile, grid 64x64
// LDS: xs 32*20*22*4 + ys 32*18*20*4 + wl 288*32*4 = 139,264 B (1 block/CU)
// ---------------------------------------------------------------------------
__global__ __launch_bounds__(256) void conv_kernel(
    const float* __restrict__ PL, const float* __restrict__ PR,
    const float* __restrict__ cvec,
    const float* __restrict__ w1, const float* __restrict__ b1,
    const float* __restrict__ w2, const float* __restrict__ b2,
    const float* __restrict__ w3, const float* __restrict__ b3,
    float* __restrict__ outp)
{
    __shared__ float xs[32][20][22];
    __shared__ float ys[32][18][20];
    __shared__ float wl[288][32];    // [ci*9+dy*3+dx][co]
    const int t   = threadIdx.x;
    const int oy0 = blockIdx.y * 16;
    const int ox0 = blockIdx.x * 16;

    // ---- stage x0 tile (rows oy0-2..oy0+17, cols ox0-2..ox0+19) ----
    for (int idx = t; idx < 32 * 20 * 22; idx += 256){
        int ci = idx & 31;
        int p  = idx >> 5;            // 0..439
        int ry = p / 22, rx = p % 22;
        int a = oy0 - 2 + ry, b = ox0 - 2 + rx;
        float v = 0.f;
        if (a >= 0 && a < 1024 && b >= 0 && b < 1024)
            v = PL[(size_t)a * 32 + ci] + PR[(size_t)b * 32 + ci] + cvec[ci];
        xs[ci][ry][rx] = v;
    }
    // ---- stage conv1 weights (coalesced read, scattered LDS write) ----
    for (int e = t; e < 9216; e += 256){
        int co = e / 288; int k = e - co * 288;
        wl[k][co] = w1[e];
    }
    __syncthreads();

    const int cg   = t >> 6;     // wave id = co group (co = cg*8..cg*8+7)
    const int lane = t & 63;

    // conv1: y1 tile is 18 rows x 20 cols (but only cols 0..17 are consumed);
    // strips: 18 rows x 5 strips-of-4 = 90; lane does strips lane, lane+64
    const int s0 = lane;
    const int s1 = lane + 64;
    const bool act1 = (s1 < 90);
    const int r0 = s0 / 5, c0 = (s0 % 5) * 4;
    const int r1 = act1 ? s1 / 5 : 0, c1 = act1 ? (s1 % 5) * 4 : 0;

    float acc0[8][4], acc1[8][4];
    #pragma unroll
    for (int c = 0; c < 8; ++c){
        float bb = b1[cg * 8 + c];
        #pragma unroll
        for (int p = 0; p < 4; ++p){ acc0[c][p] = bb; acc1[c][p] = bb; }
    }

    for (int ci = 0; ci < 32; ++ci){
        #pragma unroll
        for (int dy = 0; dy < 3; ++dy){
            const float* xr0 = &xs[ci][r0 + dy][c0];
            const float* xr1 = &xs[ci][r1 + dy][c1];
            float v0[6], v1[6];
            #pragma unroll
            for (int q = 0; q < 3; ++q){
                float2 t0 = *reinterpret_cast<const float2*>(xr0 + 2 * q);
                float2 t1 = *reinterpret_cast<const float2*>(xr1 + 2 * q);
                v0[2*q] = t0.x; v0[2*q+1] = t0.y;
                v1[2*q] = t1.x; v1[2*q+1] = t1.y;
            }
            const float* wb = &wl[ci * 9 + dy * 3][cg * 8];
            #pragma unroll
            for (int dx = 0; dx < 3; ++dx){
                float wv[8];
                *reinterpret_cast<float4*>(wv)     = *reinterpret_cast<const float4*>(wb + dx * 32);
                *reinterpret_cast<float4*>(wv + 4) = *reinterpret_cast<const float4*>(wb + dx * 32 + 4);
                #pragma unroll
                for (int c = 0; c < 8; ++c)
                    #pragma unroll
                    for (int p = 0; p < 4; ++p){
                        acc0[c][p] = fmaf(wv[c], v0[p + dx], acc0[c][p]);
                        acc1[c][p] = fmaf(wv[c], v1[p + dx], acc1[c][p]);
                    }
            }
        }
    }

    // write y1 (relu, zero outside the 1024x1024 image); ys rows=oy0-1..oy0+16
    #pragma unroll
    for (int slot = 0; slot < 2; ++slot){
        if (slot == 1 && !act1) break;
        int r  = slot ? r1 : r0;
        int cc = slot ? c1 : c0;
        int gy = oy0 - 1 + r;
        bool rowok = (gy >= 0 && gy < 1024);
        #pragma unroll
        for (int p = 0; p < 4; ++p){
            int col = cc + p;
            if (col >= 18) continue;           // cols 18,19 never consumed
            int gx = ox0 - 1 + col;
            bool ok = rowok && (gx >= 0) && (gx < 1024);
            #pragma unroll
            for (int c = 0; c < 8; ++c){
                float v = slot ? acc1[c][p] : acc0[c][p];
                ys[cg * 8 + c][r][col] = ok ? fmaxf(v, 0.f) : 0.f;
            }
        }
    }
    __syncthreads();
    // ---- restage weights for conv2 ----
    for (int e = t; e < 9216; e += 256){
        int co = e / 288; int k = e - co * 288;
        wl[k][co] = w2[e];
    }
    __syncthreads();

    // conv2: 16x16 outputs = 64 strips of 4, one per lane
    const int r2 = lane >> 2;
    const int c2 = (lane & 3) * 4;
    float a2[8][4];
    #pragma unroll
    for (int c = 0; c < 8; ++c){
        float bb = b2[cg * 8 + c];
        #pragma unroll
        for (int p = 0; p < 4; ++p) a2[c][p] = bb;
    }
    for (int ci = 0; ci < 32; ++ci){
        #pragma unroll
        for (int dy = 0; dy < 3; ++dy){
            const float* yr = &ys[ci][r2 + dy][c2];
            float v[6];
            #pragma unroll
            for (int q = 0; q < 3; ++q){
                float2 tv = *reinterpret_cast<const float2*>(yr + 2 * q);
                v[2*q] = tv.x; v[2*q+1] = tv.y;
            }
            const float* wb = &wl[ci * 9 + dy * 3][cg * 8];
            #pragma unroll
            for (int dx = 0; dx < 3; ++dx){
                float wv[8];
                *reinterpret_cast<float4*>(wv)     = *reinterpret_cast<const float4*>(wb + dx * 32);
                *reinterpret_cast<float4*>(wv + 4) = *reinterpret_cast<const float4*>(wb + dx * 32 + 4);
                #pragma unroll
                for (int c = 0; c < 8; ++c)
                    #pragma unroll
                    for (int p = 0; p < 4; ++p)
                        a2[c][p] = fmaf(wv[c], v[p + dx], a2[c][p]);
            }
        }
    }
    // conv3 (1x1): partial over this wave's 8 channels, relu applied to a2
    float prt[4] = {0.f, 0.f, 0.f, 0.f};
    #pragma unroll
    for (int c = 0; c < 8; ++c){
        float w3v = w3[cg * 8 + c];
        #pragma unroll
        for (int p = 0; p < 4; ++p)
            prt[p] = fmaf(w3v, fmaxf(a2[c][p], 0.f), prt[p]);
    }
    __syncthreads();
    float* red = &xs[0][0][0];   // reuse xs
    #pragma unroll
    for (int p = 0; p < 4; ++p)
        red[(p * 4 + cg) * 64 + lane] = prt[p];
    __syncthreads();
    {
        int li = t >> 2, p = t & 3;
        float s = red[(p * 4 + 0) * 64 + li] + red[(p * 4 + 1) * 64 + li]
                + red[(p * 4 + 2) * 64 + li] + red[(p * 4 + 3) * 64 + li];
        s += b3[0];
        int gy = oy0 + (li >> 2);
        int gx = ox0 + (li & 3) * 4 + p;
        outp[(size_t)gy * 1024 + gx] = s;
    }
}

// ---------------------------------------------------------------------------
extern "C" void kernel_launch(void* const* d_in, const int* in_sizes, int n_in,
                              void* d_out, int out_size, void* d_ws, size_t ws_size,
                              hipStream_t stream)
{
    const float* lig_nf = (const float*)d_in[0];
    const float* lig_ef = (const float*)d_in[1];
    const float* rec_nf = (const float*)d_in[3];
    const float* rec_ef = (const float*)d_in[4];
    const float* Wn     = (const float*)d_in[6];
    const float* bn     = (const float*)d_in[7];
    const float* We     = (const float*)d_in[8];
    const float* be     = (const float*)d_in[9];
    const float* W_hopi = (const float*)d_in[12];
    const float* b_hopi = (const float*)d_in[13];
    const float* w1     = (const float*)d_in[14];
    const float* b1     = (const float*)d_in[15];
    const float* w2     = (const float*)d_in[16];
    const float* b2     = (const float*)d_in[17];
    const float* w3     = (const float*)d_in[18];
    const float* b3     = (const float*)d_in[19];
    float* outp = (float*)d_out;

    float* part = (float*)d_ws;                               // [2][16][1024] f32
    float* PL   = (float*)((char*)d_ws + 131072);             // 1024*32 f32
    float* PR   = (float*)((char*)d_ws + 262144);             // 1024*32 f32
    float* cvec = (float*)((char*)d_ws + 393216);             // 32 f32

    dim3 g1(8, 16, 2);
    gnn_kernel<<<g1, 256, 0, stream>>>(lig_nf, lig_ef, rec_nf, rec_ef,
                                       Wn, We, bn, be, part);
    dim3 g2(128, 2);
    proj_kernel<<<g2, 256, 0, stream>>>(lig_nf, rec_nf, W_hopi, PL, PR);
    cvec_kernel<<<1, 256, 0, stream>>>(W_hopi, b_hopi, part, cvec);
    dim3 g3(64, 64);
    conv_kernel<<<g3, 256, 0, stream>>>(PL, PR, cvec, w1, b1, w2, b2, w3, b3, outp);
}

// Round 3
// 364.839 us; speedup vs baseline: 3.7460x; 3.7460x over previous
//
#include <hip/hip_runtime.h>

// All tensors float32. Math structure exploited:
//  - softmax over axis of size 1 == 1.0 -> attn all-ones, Wa/ba dead.
//  - weighted = row-sum of tanh(agg), broadcast over COLUMNS (N==D quirk).
//  - lig_p = nf@Wl.T + const  ->  x0[h,i,j] = PL[i,h] + PR[j,h] + c[h]
//  - conv1/2/3 fully fused, x0 generated on the fly (no 128MB tensor),
//    conv compute on f16 MFMA (matrix pipe), f32 accumulate.

typedef _Float16 half8 __attribute__((ext_vector_type(8)));
typedef float    f32x4 __attribute__((ext_vector_type(4)));

__device__ __forceinline__ short f2h_bits(float f){
    _Float16 h = (_Float16)f;          // RNE
    return __builtin_bit_cast(short, h);
}

// ci-block swizzle: XOR bits 3..4 of the ci index with (col>>1)&3
#define SWZ(c) ((((c) >> 1) & 3) << 3)

// ---------------------------------------------------------------------------
// K1: agg = tanh(nf@Wn.T + bn + ef@We.T + be); partial row-sums over d-blocks.
// Tiled f32 GEMM: BM=128, BN=64, BK=32, 256 thr, micro 8x4. grid (8,16,2)
// ---------------------------------------------------------------------------
__global__ __launch_bounds__(256) void gnn_kernel(
    const float* __restrict__ lig_nf, const float* __restrict__ lig_ef,
    const float* __restrict__ rec_nf, const float* __restrict__ rec_ef,
    const float* __restrict__ Wn, const float* __restrict__ We,
    const float* __restrict__ bn, const float* __restrict__ be,
    float* __restrict__ part)   // [2][16][1024]
{
    __shared__ float As[32][128];
    __shared__ float Bs[32][64];
    const int t  = threadIdx.x;
    const int cx = blockIdx.z;
    const float* A0 = cx ? rec_nf : lig_nf;
    const float* A1 = cx ? rec_ef : lig_ef;
    const int j0 = blockIdx.x * 128;
    const int d0 = blockIdx.y * 64;

    float acc[8][4];
    #pragma unroll
    for (int i = 0; i < 8; ++i)
        #pragma unroll
        for (int j = 0; j < 4; ++j) acc[i][j] = 0.f;

    const int ty = t >> 4;
    const int tx = t & 15;

    for (int kt = 0; kt < 64; ++kt){
        const float* Asrc = (kt < 32) ? A0 : A1;
        const float* Bsrc = (kt < 32) ? Wn : We;
        const int kb = (kt & 31) * 32;
        #pragma unroll
        for (int p = 0; p < 4; ++p){
            int u   = t + 256 * p;
            int row = u >> 3;
            int kc  = (u & 7) * 4;
            float4 v = *reinterpret_cast<const float4*>(Asrc + (size_t)(j0 + row) * 1024 + kb + kc);
            As[kc + 0][row] = v.x; As[kc + 1][row] = v.y;
            As[kc + 2][row] = v.z; As[kc + 3][row] = v.w;
        }
        #pragma unroll
        for (int p = 0; p < 2; ++p){
            int u   = t + 256 * p;
            int row = u >> 3;
            int kc  = (u & 7) * 4;
            float4 v = *reinterpret_cast<const float4*>(Bsrc + (size_t)(d0 + row) * 1024 + kb + kc);
            Bs[kc + 0][row] = v.x; Bs[kc + 1][row] = v.y;
            Bs[kc + 2][row] = v.z; Bs[kc + 3][row] = v.w;
        }
        __syncthreads();
        #pragma unroll
        for (int kk = 0; kk < 32; ++kk){
            float4 a0 = *reinterpret_cast<const float4*>(&As[kk][ty * 8]);
            float4 a1 = *reinterpret_cast<const float4*>(&As[kk][ty * 8 + 4]);
            float4 b  = *reinterpret_cast<const float4*>(&Bs[kk][tx * 4]);
            float av[8] = {a0.x, a0.y, a0.z, a0.w, a1.x, a1.y, a1.z, a1.w};
            float bv[4] = {b.x, b.y, b.z, b.w};
            #pragma unroll
            for (int i = 0; i < 8; ++i)
                #pragma unroll
                for (int j = 0; j < 4; ++j)
                    acc[i][j] = fmaf(av[i], bv[j], acc[i][j]);
        }
        __syncthreads();
    }

    float rsum[8];
    #pragma unroll
    for (int i = 0; i < 8; ++i) rsum[i] = 0.f;
    #pragma unroll
    for (int j = 0; j < 4; ++j){
        int d = d0 + tx * 4 + j;
        float bias = bn[d] + be[d];
        #pragma unroll
        for (int i = 0; i < 8; ++i)
            rsum[i] += tanhf(acc[i][j] + bias);
    }
    #pragma unroll
    for (int m = 1; m < 16; m <<= 1)
        #pragma unroll
        for (int i = 0; i < 8; ++i)
            rsum[i] += __shfl_xor(rsum[i], m);
    if (tx == 0){
        float* p = part + (size_t)cx * 16384 + (size_t)blockIdx.y * 1024;
        #pragma unroll
        for (int i = 0; i < 8; ++i)
            p[j0 + ty * 8 + i] = rsum[i];
    }
}

// ---------------------------------------------------------------------------
// K2a: PL[i,h] = sum_j nf[i,j]*Wl[h,j]; PR analog. grid (128,2), block 256
// ---------------------------------------------------------------------------
__global__ __launch_bounds__(256) void proj_kernel(
    const float* __restrict__ lig_nf, const float* __restrict__ rec_nf,
    const float* __restrict__ W_hopi, float* __restrict__ PL, float* __restrict__ PR)
{
    const int t  = threadIdx.x;
    const int cx = blockIdx.y;
    const float* nf = cx ? rec_nf : lig_nf;
    const float* W  = W_hopi + (cx ? 1024 : 0);
    float* outp     = cx ? PR : PL;
    const int h = t & 31;
    const int i = blockIdx.x * 8 + (t >> 5);
    const float* nrow = nf + (size_t)i * 1024;
    const float* wrow = W + (size_t)h * 2048;
    float s0 = 0.f, s1 = 0.f;
    #pragma unroll 4
    for (int j = 0; j < 1024; j += 8){
        float4 a0 = *reinterpret_cast<const float4*>(nrow + j);
        float4 b0 = *reinterpret_cast<const float4*>(wrow + j);
        float4 a1 = *reinterpret_cast<const float4*>(nrow + j + 4);
        float4 b1 = *reinterpret_cast<const float4*>(wrow + j + 4);
        s0 = fmaf(a0.x, b0.x, s0); s0 = fmaf(a0.y, b0.y, s0);
        s0 = fmaf(a0.z, b0.z, s0); s0 = fmaf(a0.w, b0.w, s0);
        s1 = fmaf(a1.x, b1.x, s1); s1 = fmaf(a1.y, b1.y, s1);
        s1 = fmaf(a1.z, b1.z, s1); s1 = fmaf(a1.w, b1.w, s1);
    }
    outp[(size_t)i * 32 + h] = s0 + s1;
}

// ---------------------------------------------------------------------------
// K2b: w[j] = block-sum of part; c[h] = b_hopi[h] + wL.Wl[h] + wR.Wr[h]
// ---------------------------------------------------------------------------
__global__ __launch_bounds__(256) void cvec_kernel(
    const float* __restrict__ W_hopi, const float* __restrict__ b_hopi,
    const float* __restrict__ part, float* __restrict__ cvec)
{
    __shared__ float ws_l[1024];
    __shared__ float ws_r[1024];
    __shared__ float red[256];
    const int t = threadIdx.x;
    for (int j = t; j < 1024; j += 256){
        float sl = 0.f, sr = 0.f;
        #pragma unroll
        for (int b = 0; b < 16; ++b){
            sl += part[b * 1024 + j];
            sr += part[16384 + b * 1024 + j];
        }
        ws_l[j] = sl; ws_r[j] = sr;
    }
    __syncthreads();
    const int h = t & 31;
    const int seg = t >> 5;
    float s = 0.f;
    for (int j = seg * 128; j < seg * 128 + 128; ++j){
        s = fmaf(ws_l[j], W_hopi[(size_t)h * 2048 + j], s);
        s = fmaf(ws_r[j], W_hopi[(size_t)h * 2048 + 1024 + j], s);
    }
    red[t] = s;
    __syncthreads();
    if (t < 32){
        float tot = b_hopi[t];
        #pragma unroll
        for (int g = 0; g < 8; ++g) tot += red[g * 32 + t];
        cvec[t] = tot;
    }
}

// ---------------------------------------------------------------------------
// K3: fused conv1+relu -> conv2+relu -> conv3 on f16 MFMA.
// Implicit GEMM per 16x16 tile: M=pixels, N=32 co, K=288 (9 taps x 32 ci,
// ci-innermost). Every A/B fragment = one ds_read_b128 (ci-block swizzled).
// block = 512 thr (8 waves), grid 64x64. LDS = 64,768 B.
//   xs[20][20][32]: x0 halo tile (f16), xs[a][b][ci^SWZ(b)]
//   ys[18x18][32] : conv1 out (f16),    ys[p][co^SWZ(p%18)]
//   wB[9][32][32] : weights (f16),      wB[tap][co][ci^SWZ(co)]
// ---------------------------------------------------------------------------
__global__ __launch_bounds__(512) void conv_kernel(
    const float* __restrict__ PL, const float* __restrict__ PR,
    const float* __restrict__ cvec,
    const float* __restrict__ w1, const float* __restrict__ b1,
    const float* __restrict__ w2, const float* __restrict__ b2,
    const float* __restrict__ w3, const float* __restrict__ b3,
    float* __restrict__ outp)
{
    __shared__ __attribute__((aligned(16))) short xs[20 * 20 * 32];
    __shared__ __attribute__((aligned(16))) short ys[18 * 18 * 32];
    __shared__ __attribute__((aligned(16))) short wB[9 * 32 * 32];

    const int t    = threadIdx.x;
    const int oy0  = blockIdx.y * 16;
    const int ox0  = blockIdx.x * 16;
    const int wid  = t >> 6;
    const int lane = t & 63;
    const int lr   = lane & 15;   // fragment row (A: pixel, B: co)
    const int lg   = lane >> 4;   // k-group (ci block)

    // ---- stage x0 tile: 400 pixels x 32 ci, 16 threads per pixel ----
    {
        const int grp = t >> 4;           // pixel slot per pass (32/pass)
        const int cp  = (t & 15) * 2;     // ci pair
        #pragma unroll
        for (int pass = 0; pass < 13; ++pass){
            int pp = grp + pass * 32;
            if (pp < 400){
                int ry = pp / 20, rx = pp - ry * 20;
                int a = oy0 - 2 + ry, b = ox0 - 2 + rx;
                float v0 = 0.f, v1 = 0.f;
                if (a >= 0 && a < 1024 && b >= 0 && b < 1024){
                    float2 pl = *reinterpret_cast<const float2*>(PL + a * 32 + cp);
                    float2 pr = *reinterpret_cast<const float2*>(PR + b * 32 + cp);
                    float2 cv = *reinterpret_cast<const float2*>(cvec + cp);
                    v0 = pl.x + pr.x + cv.x;
                    v1 = pl.y + pr.y + cv.y;
                }
                int addr = pp * 32 + (cp ^ SWZ(rx));
                *reinterpret_cast<short2*>(&xs[addr]) =
                    make_short2(f2h_bits(v0), f2h_bits(v1));
            }
        }
    }
    // ---- stage conv1 weights ----
    for (int e = t; e < 9216; e += 512){
        int co  = e / 288;
        int rem = e - co * 288;
        int ci  = rem / 9;
        int tap = rem - ci * 9;
        wB[(tap * 32 + co) * 32 + (ci ^ SWZ(co))] = f2h_bits(w1[e]);
    }
    __syncthreads();

    // ================= conv1: 324 outputs (18x18), 21 M-subtiles =========
    {
        half8 Bf[2][9];
        float bias[2];
        #pragma unroll
        for (int n = 0; n < 2; ++n){
            int co = n * 16 + lr;
            bias[n] = b1[co];
            #pragma unroll
            for (int tap = 0; tap < 9; ++tap)
                Bf[n][tap] = *reinterpret_cast<const half8*>(
                    &wB[(tap * 32 + co) * 32 + ((lg * 8) ^ SWZ(co))]);
        }
        for (int s = wid; s < 21; s += 8){
            int praw = s * 16 + lr;
            int p  = praw > 323 ? 323 : praw;
            int ry = p / 18;
            int rx = p - ry * 18;
            f32x4 acc0 = {0.f, 0.f, 0.f, 0.f};
            f32x4 acc1 = {0.f, 0.f, 0.f, 0.f};
            #pragma unroll
            for (int tap = 0; tap < 9; ++tap){
                const int dy = tap / 3, dx = tap - (tap / 3) * 3;
                int pix = (ry + dy) * 20 + rx + dx;
                half8 A = *reinterpret_cast<const half8*>(
                    &xs[pix * 32 + ((lg * 8) ^ SWZ(rx + dx))]);
                acc0 = __builtin_amdgcn_mfma_f32_16x16x32_f16(A, Bf[0][tap], acc0, 0, 0, 0);
                acc1 = __builtin_amdgcn_mfma_f32_16x16x32_f16(A, Bf[1][tap], acc1, 0, 0, 0);
            }
            #pragma unroll
            for (int j = 0; j < 4; ++j){
                int po = s * 16 + lg * 4 + j;
                if (po < 324){
                    int ryo = po / 18;
                    int rxo = po - ryo * 18;
                    int gy = oy0 - 1 + ryo, gx = ox0 - 1 + rxo;
                    bool ok = (gy >= 0) & (gy < 1024) & (gx >= 0) & (gx < 1024);
                    float v0 = ok ? fmaxf(acc0[j] + bias[0], 0.f) : 0.f;
                    float v1 = ok ? fmaxf(acc1[j] + bias[1], 0.f) : 0.f;
                    int sw = SWZ(rxo);
                    ys[po * 32 + (lr ^ sw)]        = f2h_bits(v0);
                    ys[po * 32 + ((16 + lr) ^ sw)] = f2h_bits(v1);
                }
            }
        }
    }
    __syncthreads();
    // ---- restage weights for conv2 ----
    for (int e = t; e < 9216; e += 512){
        int co  = e / 288;
        int rem = e - co * 288;
        int ci  = rem / 9;
        int tap = rem - ci * 9;
        wB[(tap * 32 + co) * 32 + (ci ^ SWZ(co))] = f2h_bits(w2[e]);
    }
    __syncthreads();

    // ================= conv2 + conv3: 256 outputs, 16 M-subtiles =========
    {
        half8 Bf[2][9];
        float bias[2], w3v[2];
        #pragma unroll
        for (int n = 0; n < 2; ++n){
            int co = n * 16 + lr;
            bias[n] = b2[co];
            w3v[n]  = w3[co];
            #pragma unroll
            for (int tap = 0; tap < 9; ++tap)
                Bf[n][tap] = *reinterpret_cast<const half8*>(
                    &wB[(tap * 32 + co) * 32 + ((lg * 8) ^ SWZ(co))]);
        }
        const float b3v = b3[0];
        for (int s = wid; s < 16; s += 8){
            int p  = s * 16 + lr;
            int ry = p >> 4;
            int rx = p & 15;
            f32x4 acc0 = {0.f, 0.f, 0.f, 0.f};
            f32x4 acc1 = {0.f, 0.f, 0.f, 0.f};
            #pragma unroll
            for (int tap = 0; tap < 9; ++tap){
                const int dy = tap / 3, dx = tap - (tap / 3) * 3;
                int pix = (ry + dy) * 18 + rx + dx;
                half8 A = *reinterpret_cast<const half8*>(
                    &ys[pix * 32 + ((lg * 8) ^ SWZ(rx + dx))]);
                acc0 = __builtin_amdgcn_mfma_f32_16x16x32_f16(A, Bf[0][tap], acc0, 0, 0, 0);
                acc1 = __builtin_amdgcn_mfma_f32_16x16x32_f16(A, Bf[1][tap], acc1, 0, 0, 0);
            }
            // conv3 (1x1): per-lane partial over its 2 co, reduce across 16 lanes
            float part[4];
            #pragma unroll
            for (int j = 0; j < 4; ++j)
                part[j] = w3v[0] * fmaxf(acc0[j] + bias[0], 0.f)
                        + w3v[1] * fmaxf(acc1[j] + bias[1], 0.f);
            #pragma unroll
            for (int m = 1; m < 16; m <<= 1)
                #pragma unroll
                for (int j = 0; j < 4; ++j)
                    part[j] += __shfl_xor(part[j], m);
            if (lr == 0){
                float4 o = make_float4(part[0] + b3v, part[1] + b3v,
                                       part[2] + b3v, part[3] + b3v);
                *reinterpret_cast<float4*>(outp + (size_t)(oy0 + s) * 1024 + ox0 + lg * 4) = o;
            }
        }
    }
}

// ---------------------------------------------------------------------------
extern "C" void kernel_launch(void* const* d_in, const int* in_sizes, int n_in,
                              void* d_out, int out_size, void* d_ws, size_t ws_size,
                              hipStream_t stream)
{
    const float* lig_nf = (const float*)d_in[0];
    const float* lig_ef = (const float*)d_in[1];
    const float* rec_nf = (const float*)d_in[3];
    const float* rec_ef = (const float*)d_in[4];
    const float* Wn     = (const float*)d_in[6];
    const float* bn     = (const float*)d_in[7];
    const float* We     = (const float*)d_in[8];
    const float* be     = (const float*)d_in[9];
    const float* W_hopi = (const float*)d_in[12];
    const float* b_hopi = (const float*)d_in[13];
    const float* w1     = (const float*)d_in[14];
    const float* b1     = (const float*)d_in[15];
    const float* w2     = (const float*)d_in[16];
    const float* b2     = (const float*)d_in[17];
    const float* w3     = (const float*)d_in[18];
    const float* b3     = (const float*)d_in[19];
    float* outp = (float*)d_out;

    float* part = (float*)d_ws;                               // [2][16][1024]
    float* PL   = (float*)((char*)d_ws + 131072);
    float* PR   = (float*)((char*)d_ws + 262144);
    float* cvec = (float*)((char*)d_ws + 393216);

    dim3 g1(8, 16, 2);
    gnn_kernel<<<g1, 256, 0, stream>>>(lig_nf, lig_ef, rec_nf, rec_ef,
                                       Wn, We, bn, be, part);
    dim3 g2(128, 2);
    proj_kernel<<<g2, 256, 0, stream>>>(lig_nf, rec_nf, W_hopi, PL, PR);
    cvec_kernel<<<1, 256, 0, stream>>>(W_hopi, b_hopi, part, cvec);
    dim3 g3(64, 64);
    conv_kernel<<<g3, 512, 0, stream>>>(PL, PR, cvec, w1, b1, w2, b2, w3, b3, outp);
}

// Round 4
// 227.835 us; speedup vs baseline: 5.9986x; 1.6013x over previous
//
#include <hip/hip_runtime.h>

// All tensors float32. Math structure exploited:
//  - softmax over axis of size 1 == 1.0 -> attn all-ones, Wa/ba dead.
//  - weighted = row-sum of tanh(agg), broadcast over COLUMNS (N==D quirk).
//  - lig_p = nf@Wl.T + const  ->  x0[h,i,j] = PL[i,h] + PR[j,h] + c[h]
//  - conv1/2/3 fully fused, x0 generated on the fly (no 128MB tensor).
//  - gnn GEMM (M1024 x N1024 x K2048) and convs both on f16 MFMA, f32 accum.

typedef _Float16 half8 __attribute__((ext_vector_type(8)));
typedef float    f32x4 __attribute__((ext_vector_type(4)));

__device__ __forceinline__ short f2h_bits(float f){
    _Float16 h = (_Float16)f;          // RNE
    return __builtin_bit_cast(short, h);
}
__device__ __forceinline__ half8 pack2(const float4& x, const float4& y){
    half8 r;
    r[0] = (_Float16)x.x; r[1] = (_Float16)x.y;
    r[2] = (_Float16)x.z; r[3] = (_Float16)x.w;
    r[4] = (_Float16)y.x; r[5] = (_Float16)y.y;
    r[6] = (_Float16)y.z; r[7] = (_Float16)y.w;
    return r;
}

// ci-block swizzle for conv LDS tiles
#define SWZ(c) ((((c) >> 1) & 3) << 3)

// ---------------------------------------------------------------------------
// K1 (MFMA): agg = tanh([nf|ef]@[Wn|We].T + bn + be); per-block row-sums over
// its 64 d-columns -> part[cx][dblk][row]. BM=BN=64, BK=64, 256 thr (4 waves,
// wave-tile 32x32), grid (16,16,2). LDS tiles f16, granule XOR swizzle.
// ---------------------------------------------------------------------------
__global__ __launch_bounds__(256) void gnn_kernel(
    const float* __restrict__ lig_nf, const float* __restrict__ lig_ef,
    const float* __restrict__ rec_nf, const float* __restrict__ rec_ef,
    const float* __restrict__ Wn, const float* __restrict__ We,
    const float* __restrict__ bn, const float* __restrict__ be,
    float* __restrict__ part)   // [2][16][1024]
{
    __shared__ __attribute__((aligned(16))) short As[64 * 64];
    __shared__ __attribute__((aligned(16))) short Bs[64 * 64];
    __shared__ float red[64][2];

    const int t  = threadIdx.x;
    const int cx = blockIdx.z;
    const float* A0 = cx ? rec_nf : lig_nf;
    const float* A1 = cx ? rec_ef : lig_ef;
    const int j0 = blockIdx.x * 64;
    const int d0 = blockIdx.y * 64;

    const int wid  = t >> 6;
    const int wm   = wid >> 1, wn = wid & 1;
    const int lane = t & 63;
    const int lr   = lane & 15;   // A: row, B: col, C: col
    const int lg   = lane >> 4;   // k-granule / C row group

    f32x4 acc[2][2];
    #pragma unroll
    for (int m = 0; m < 2; ++m)
        #pragma unroll
        for (int n = 0; n < 2; ++n)
            acc[m][n] = (f32x4){0.f, 0.f, 0.f, 0.f};

    const int srow   = t >> 2;    // staging row 0..63
    const int schunk = t & 3;     // 16-float chunk of the 64-wide K slab
    const int sswz   = srow & 7;

    for (int kb = 0; kb < 2048; kb += 64){
        const float* Asrc = (kb < 1024) ? A0 : A1;
        const float* Bsrc = (kb < 1024) ? Wn : We;
        const int kcol = (kb & 1023) + schunk * 16;
        float4 av[4], bv[4];
        const float* ap = Asrc + (size_t)(j0 + srow) * 1024 + kcol;
        const float* bp = Bsrc + (size_t)(d0 + srow) * 1024 + kcol;
        #pragma unroll
        for (int q = 0; q < 4; ++q){
            av[q] = *reinterpret_cast<const float4*>(ap + q * 4);
            bv[q] = *reinterpret_cast<const float4*>(bp + q * 4);
        }
        __syncthreads();   // previous iter's LDS reads done
        const int g0 = ((schunk * 2)     ^ sswz) * 8;
        const int g1 = ((schunk * 2 + 1) ^ sswz) * 8;
        *reinterpret_cast<half8*>(&As[srow * 64 + g0]) = pack2(av[0], av[1]);
        *reinterpret_cast<half8*>(&As[srow * 64 + g1]) = pack2(av[2], av[3]);
        *reinterpret_cast<half8*>(&Bs[srow * 64 + g0]) = pack2(bv[0], bv[1]);
        *reinterpret_cast<half8*>(&Bs[srow * 64 + g1]) = pack2(bv[2], bv[3]);
        __syncthreads();

        #pragma unroll
        for (int ks = 0; ks < 2; ++ks){
            half8 Af[2], Bf[2];
            #pragma unroll
            for (int m = 0; m < 2; ++m){
                int row = wm * 32 + m * 16 + lr;
                int g   = ((ks * 4 + lg) ^ (row & 7)) * 8;
                Af[m] = *reinterpret_cast<const half8*>(&As[row * 64 + g]);
            }
            #pragma unroll
            for (int n = 0; n < 2; ++n){
                int col = wn * 32 + n * 16 + lr;
                int g   = ((ks * 4 + lg) ^ (col & 7)) * 8;
                Bf[n] = *reinterpret_cast<const half8*>(&Bs[col * 64 + g]);
            }
            #pragma unroll
            for (int m = 0; m < 2; ++m)
                #pragma unroll
                for (int n = 0; n < 2; ++n)
                    acc[m][n] = __builtin_amdgcn_mfma_f32_16x16x32_f16(
                        Af[m], Bf[n], acc[m][n], 0, 0, 0);
        }
    }

    // epilogue: bias + tanh + reduce over the block's 64 d-columns
    float rowsum[2][4];
    #pragma unroll
    for (int m = 0; m < 2; ++m)
        #pragma unroll
        for (int jj = 0; jj < 4; ++jj) rowsum[m][jj] = 0.f;
    #pragma unroll
    for (int n = 0; n < 2; ++n){
        int d = d0 + wn * 32 + n * 16 + lr;
        float bias = bn[d] + be[d];
        #pragma unroll
        for (int m = 0; m < 2; ++m)
            #pragma unroll
            for (int jj = 0; jj < 4; ++jj)
                rowsum[m][jj] += tanhf(acc[m][n][jj] + bias);
    }
    #pragma unroll
    for (int mask = 1; mask < 16; mask <<= 1)
        #pragma unroll
        for (int m = 0; m < 2; ++m)
            #pragma unroll
            for (int jj = 0; jj < 4; ++jj)
                rowsum[m][jj] += __shfl_xor(rowsum[m][jj], mask);
    __syncthreads();
    if (lr == 0){
        #pragma unroll
        for (int m = 0; m < 2; ++m)
            #pragma unroll
            for (int jj = 0; jj < 4; ++jj)
                red[wm * 32 + m * 16 + lg * 4 + jj][wn] = rowsum[m][jj];
    }
    __syncthreads();
    if (t < 64)
        part[(size_t)cx * 16384 + (size_t)blockIdx.y * 1024 + j0 + t]
            = red[t][0] + red[t][1];
}

// ---------------------------------------------------------------------------
// K2a: PL[i,h] = sum_j nf[i,j]*Wl[h,j]; PR analog. grid (128,2), block 256
// ---------------------------------------------------------------------------
__global__ __launch_bounds__(256) void proj_kernel(
    const float* __restrict__ lig_nf, const float* __restrict__ rec_nf,
    const float* __restrict__ W_hopi, float* __restrict__ PL, float* __restrict__ PR)
{
    const int t  = threadIdx.x;
    const int cx = blockIdx.y;
    const float* nf = cx ? rec_nf : lig_nf;
    const float* W  = W_hopi + (cx ? 1024 : 0);
    float* outp     = cx ? PR : PL;
    const int h = t & 31;
    const int i = blockIdx.x * 8 + (t >> 5);
    const float* nrow = nf + (size_t)i * 1024;
    const float* wrow = W + (size_t)h * 2048;
    float s0 = 0.f, s1 = 0.f;
    #pragma unroll 4
    for (int j = 0; j < 1024; j += 8){
        float4 a0 = *reinterpret_cast<const float4*>(nrow + j);
        float4 b0 = *reinterpret_cast<const float4*>(wrow + j);
        float4 a1 = *reinterpret_cast<const float4*>(nrow + j + 4);
        float4 b1 = *reinterpret_cast<const float4*>(wrow + j + 4);
        s0 = fmaf(a0.x, b0.x, s0); s0 = fmaf(a0.y, b0.y, s0);
        s0 = fmaf(a0.z, b0.z, s0); s0 = fmaf(a0.w, b0.w, s0);
        s1 = fmaf(a1.x, b1.x, s1); s1 = fmaf(a1.y, b1.y, s1);
        s1 = fmaf(a1.z, b1.z, s1); s1 = fmaf(a1.w, b1.w, s1);
    }
    outp[(size_t)i * 32 + h] = s0 + s1;
}

// ---------------------------------------------------------------------------
// K2b: w[j] = block-sum of part; c[h] = b_hopi[h] + wL.Wl[h] + wR.Wr[h]
// ---------------------------------------------------------------------------
__global__ __launch_bounds__(256) void cvec_kernel(
    const float* __restrict__ W_hopi, const float* __restrict__ b_hopi,
    const float* __restrict__ part, float* __restrict__ cvec)
{
    __shared__ float ws_l[1024];
    __shared__ float ws_r[1024];
    __shared__ float red[256];
    const int t = threadIdx.x;
    for (int j = t; j < 1024; j += 256){
        float sl = 0.f, sr = 0.f;
        #pragma unroll
        for (int b = 0; b < 16; ++b){
            sl += part[b * 1024 + j];
            sr += part[16384 + b * 1024 + j];
        }
        ws_l[j] = sl; ws_r[j] = sr;
    }
    __syncthreads();
    const int h = t & 31;
    const int seg = t >> 5;
    float s = 0.f;
    for (int j = seg * 128; j < seg * 128 + 128; ++j){
        s = fmaf(ws_l[j], W_hopi[(size_t)h * 2048 + j], s);
        s = fmaf(ws_r[j], W_hopi[(size_t)h * 2048 + 1024 + j], s);
    }
    red[t] = s;
    __syncthreads();
    if (t < 32){
        float tot = b_hopi[t];
        #pragma unroll
        for (int g = 0; g < 8; ++g) tot += red[g * 32 + t];
        cvec[t] = tot;
    }
}

// ---------------------------------------------------------------------------
// K3: fused conv1+relu -> conv2+relu -> conv3 on f16 MFMA.
// Implicit GEMM per 16x16 tile: M=pixels, N=32 co, K=288 (9 taps x 32 ci).
// block = 512 thr (8 waves), grid 64x64. LDS = 64,768 B.
// ---------------------------------------------------------------------------
__global__ __launch_bounds__(512) void conv_kernel(
    const float* __restrict__ PL, const float* __restrict__ PR,
    const float* __restrict__ cvec,
    const float* __restrict__ w1, const float* __restrict__ b1,
    const float* __restrict__ w2, const float* __restrict__ b2,
    const float* __restrict__ w3, const float* __restrict__ b3,
    float* __restrict__ outp)
{
    __shared__ __attribute__((aligned(16))) short xs[20 * 20 * 32];
    __shared__ __attribute__((aligned(16))) short ys[18 * 18 * 32];
    __shared__ __attribute__((aligned(16))) short wB[9 * 32 * 32];

    const int t    = threadIdx.x;
    const int oy0  = blockIdx.y * 16;
    const int ox0  = blockIdx.x * 16;
    const int wid  = t >> 6;
    const int lane = t & 63;
    const int lr   = lane & 15;
    const int lg   = lane >> 4;

    // ---- stage x0 tile: 400 pixels x 32 ci ----
    {
        const int grp = t >> 4;
        const int cp  = (t & 15) * 2;
        #pragma unroll
        for (int pass = 0; pass < 13; ++pass){
            int pp = grp + pass * 32;
            if (pp < 400){
                int ry = pp / 20, rx = pp - ry * 20;
                int a = oy0 - 2 + ry, b = ox0 - 2 + rx;
                float v0 = 0.f, v1 = 0.f;
                if (a >= 0 && a < 1024 && b >= 0 && b < 1024){
                    float2 pl = *reinterpret_cast<const float2*>(PL + a * 32 + cp);
                    float2 pr = *reinterpret_cast<const float2*>(PR + b * 32 + cp);
                    float2 cv = *reinterpret_cast<const float2*>(cvec + cp);
                    v0 = pl.x + pr.x + cv.x;
                    v1 = pl.y + pr.y + cv.y;
                }
                int addr = pp * 32 + (cp ^ SWZ(rx));
                *reinterpret_cast<short2*>(&xs[addr]) =
                    make_short2(f2h_bits(v0), f2h_bits(v1));
            }
        }
    }
    for (int e = t; e < 9216; e += 512){
        int co  = e / 288;
        int rem = e - co * 288;
        int ci  = rem / 9;
        int tap = rem - ci * 9;
        wB[(tap * 32 + co) * 32 + (ci ^ SWZ(co))] = f2h_bits(w1[e]);
    }
    __syncthreads();

    // ================= conv1: 324 outputs (18x18) =========
    {
        half8 Bf[2][9];
        float bias[2];
        #pragma unroll
        for (int n = 0; n < 2; ++n){
            int co = n * 16 + lr;
            bias[n] = b1[co];
            #pragma unroll
            for (int tap = 0; tap < 9; ++tap)
                Bf[n][tap] = *reinterpret_cast<const half8*>(
                    &wB[(tap * 32 + co) * 32 + ((lg * 8) ^ SWZ(co))]);
        }
        for (int s = wid; s < 21; s += 8){
            int praw = s * 16 + lr;
            int p  = praw > 323 ? 323 : praw;
            int ry = p / 18;
            int rx = p - ry * 18;
            f32x4 acc0 = {0.f, 0.f, 0.f, 0.f};
            f32x4 acc1 = {0.f, 0.f, 0.f, 0.f};
            #pragma unroll
            for (int tap = 0; tap < 9; ++tap){
                const int dy = tap / 3, dx = tap - (tap / 3) * 3;
                int pix = (ry + dy) * 20 + rx + dx;
                half8 A = *reinterpret_cast<const half8*>(
                    &xs[pix * 32 + ((lg * 8) ^ SWZ(rx + dx))]);
                acc0 = __builtin_amdgcn_mfma_f32_16x16x32_f16(A, Bf[0][tap], acc0, 0, 0, 0);
                acc1 = __builtin_amdgcn_mfma_f32_16x16x32_f16(A, Bf[1][tap], acc1, 0, 0, 0);
            }
            #pragma unroll
            for (int j = 0; j < 4; ++j){
                int po = s * 16 + lg * 4 + j;
                if (po < 324){
                    int ryo = po / 18;
                    int rxo = po - ryo * 18;
                    int gy = oy0 - 1 + ryo, gx = ox0 - 1 + rxo;
                    bool ok = (gy >= 0) & (gy < 1024) & (gx >= 0) & (gx < 1024);
                    float v0 = ok ? fmaxf(acc0[j] + bias[0], 0.f) : 0.f;
                    float v1 = ok ? fmaxf(acc1[j] + bias[1], 0.f) : 0.f;
                    int sw = SWZ(rxo);
                    ys[po * 32 + (lr ^ sw)]        = f2h_bits(v0);
                    ys[po * 32 + ((16 + lr) ^ sw)] = f2h_bits(v1);
                }
            }
        }
    }
    __syncthreads();
    for (int e = t; e < 9216; e += 512){
        int co  = e / 288;
        int rem = e - co * 288;
        int ci  = rem / 9;
        int tap = rem - ci * 9;
        wB[(tap * 32 + co) * 32 + (ci ^ SWZ(co))] = f2h_bits(w2[e]);
    }
    __syncthreads();

    // ================= conv2 + conv3: 256 outputs =========
    {
        half8 Bf[2][9];
        float bias[2], w3v[2];
        #pragma unroll
        for (int n = 0; n < 2; ++n){
            int co = n * 16 + lr;
            bias[n] = b2[co];
            w3v[n]  = w3[co];
            #pragma unroll
            for (int tap = 0; tap < 9; ++tap)
                Bf[n][tap] = *reinterpret_cast<const half8*>(
                    &wB[(tap * 32 + co) * 32 + ((lg * 8) ^ SWZ(co))]);
        }
        const float b3v = b3[0];
        for (int s = wid; s < 16; s += 8){
            int p  = s * 16 + lr;
            int ry = p >> 4;
            int rx = p & 15;
            f32x4 acc0 = {0.f, 0.f, 0.f, 0.f};
            f32x4 acc1 = {0.f, 0.f, 0.f, 0.f};
            #pragma unroll
            for (int tap = 0; tap < 9; ++tap){
                const int dy = tap / 3, dx = tap - (tap / 3) * 3;
                int pix = (ry + dy) * 18 + rx + dx;
                half8 A = *reinterpret_cast<const half8*>(
                    &ys[pix * 32 + ((lg * 8) ^ SWZ(rx + dx))]);
                acc0 = __builtin_amdgcn_mfma_f32_16x16x32_f16(A, Bf[0][tap], acc0, 0, 0, 0);
                acc1 = __builtin_amdgcn_mfma_f32_16x16x32_f16(A, Bf[1][tap], acc1, 0, 0, 0);
            }
            float part[4];
            #pragma unroll
            for (int j = 0; j < 4; ++j)
                part[j] = w3v[0] * fmaxf(acc0[j] + bias[0], 0.f)
                        + w3v[1] * fmaxf(acc1[j] + bias[1], 0.f);
            #pragma unroll
            for (int m = 1; m < 16; m <<= 1)
                #pragma unroll
                for (int j = 0; j < 4; ++j)
                    part[j] += __shfl_xor(part[j], m);
            if (lr == 0){
                float4 o = make_float4(part[0] + b3v, part[1] + b3v,
                                       part[2] + b3v, part[3] + b3v);
                *reinterpret_cast<float4*>(outp + (size_t)(oy0 + s) * 1024 + ox0 + lg * 4) = o;
            }
        }
    }
}

// ---------------------------------------------------------------------------
extern "C" void kernel_launch(void* const* d_in, const int* in_sizes, int n_in,
                              void* d_out, int out_size, void* d_ws, size_t ws_size,
                              hipStream_t stream)
{
    const float* lig_nf = (const float*)d_in[0];
    const float* lig_ef = (const float*)d_in[1];
    const float* rec_nf = (const float*)d_in[3];
    const float* rec_ef = (const float*)d_in[4];
    const float* Wn     = (const float*)d_in[6];
    const float* bn     = (const float*)d_in[7];
    const float* We     = (const float*)d_in[8];
    const float* be     = (const float*)d_in[9];
    const float* W_hopi = (const float*)d_in[12];
    const float* b_hopi = (const float*)d_in[13];
    const float* w1     = (const float*)d_in[14];
    const float* b1     = (const float*)d_in[15];
    const float* w2     = (const float*)d_in[16];
    const float* b2     = (const float*)d_in[17];
    const float* w3     = (const float*)d_in[18];
    const float* b3     = (const float*)d_in[19];
    float* outp = (float*)d_out;

    float* part = (float*)d_ws;                               // [2][16][1024]
    float* PL   = (float*)((char*)d_ws + 131072);
    float* PR   = (float*)((char*)d_ws + 262144);
    float* cvec = (float*)((char*)d_ws + 393216);

    dim3 g1(16, 16, 2);
    gnn_kernel<<<g1, 256, 0, stream>>>(lig_nf, lig_ef, rec_nf, rec_ef,
                                       Wn, We, bn, be, part);
    dim3 g2(128, 2);
    proj_kernel<<<g2, 256, 0, stream>>>(lig_nf, rec_nf, W_hopi, PL, PR);
    cvec_kernel<<<1, 256, 0, stream>>>(W_hopi, b_hopi, part, cvec);
    dim3 g3(64, 64);
    conv_kernel<<<g3, 512, 0, stream>>>(PL, PR, cvec, w1, b1, w2, b2, w3, b3, outp);
}